// Round 8
// baseline (326.828 us; speedup 1.0000x reference)
//
#include <hip/hip_runtime.h>
#include <math.h>

// MAM dense: C[m,n] = max_k(A[m,k]*W[n,k]) + min_k(A[m,k]*W[n,k]) + bias[n]
// A: [M,K] fp32, W: [N,K] fp32 (torch layout), C: [M,N]
//
// R8 (= R7 resubmit after infra failure): lane=m, LDS-free, W through VMEM.
// R6 post-mortem: W via s_load thrashed K$ (16 loads/j, 4 KB apart) and
// lgkmcnt(0) coarse waits killed the pipeline (~75% stall). Both A and W are
// pre-transposed to k-major ([j][row] of float4); W loaded as 8
// uniform-address global_load_dwordx4 (VGPR address forced via v_mov 0) ->
// in-order vmcnt fine waits, TA broadcasts same-address loads. Per-CU model:
// VALU 98k cyc (41 us), VMEM issue 37k, L2 A-traffic ~31 us -> VALU-bound.

typedef float f32x2 __attribute__((ext_vector_type(2)));

static __device__ __forceinline__ f32x2 pkmul(f32x2 a, f32x2 w) {
    f32x2 d;
    asm("v_pk_mul_f32 %0, %1, %2" : "=v"(d) : "v"(a), "v"(w));
    return d;
}
static __device__ __forceinline__ void upd(float& mx, float& mn, f32x2 p) {
    float nmx, nmn;
    asm("v_max3_f32 %0, %1, %2, %3" : "=v"(nmx) : "v"(p.x), "v"(p.y), "v"(mx));
    asm("v_min3_f32 %0, %1, %2, %3" : "=v"(nmn) : "v"(p.x), "v"(p.y), "v"(mn));
    mx = nmx;
    mn = nmn;
}

// ---- pre-pass: Rt4[j][r] = (X[r][4j..4j+3]) for row-major X[R][K] ----
__global__ __launch_bounds__(256) void transpose_k4(
    const float* __restrict__ X, float4* __restrict__ out, int R, int K)
{
    __shared__ float4 T[16][65];
    const int t = threadIdx.x;
    const int r = t >> 3;        // 0..31
    const int c = t & 7;         // 0..7
    const int r0 = blockIdx.y * 64;
    const int k0 = blockIdx.x * 64;

    const float4* Xr0 = (const float4*)(X + (size_t)(r0 + r) * K + k0);
    const float4* Xr1 = (const float4*)(X + (size_t)(r0 + r + 32) * K + k0);
    T[c][r]          = Xr0[c];
    T[c + 8][r]      = Xr0[c + 8];
    T[c][r + 32]     = Xr1[c];
    T[c + 8][r + 32] = Xr1[c + 8];
    __syncthreads();

    const int rl = t & 63;
    const int jq = t >> 6;       // 0..3
    const int j0 = blockIdx.x * 16;
#pragma unroll
    for (int q = 0; q < 4; ++q) {
        const int jl = jq * 4 + q;
        out[(size_t)(j0 + jl) * R + r0 + rl] = T[jl][rl];
    }
}

// ---- main: no LDS, no barriers, no SMEM data loads ----
__global__ __launch_bounds__(256, 4) void mam_main(
    const float4* __restrict__ at4, const float4* __restrict__ wt4,
    const float* __restrict__ bias, float* __restrict__ C,
    int M, int N, int K)
{
    const int t  = threadIdx.x;
    const int m  = blockIdx.y * 256 + t;   // lane-m, coalesced
    const int n0 = blockIdx.x * 8;

    // force a VGPR-based address for W so loads stay on the VMEM pipe
    int vzero;
    asm("v_mov_b32 %0, 0" : "=v"(vzero));
    const float4* wt4v = wt4 + n0 + vzero;

    float mx[8], mn[8];
#pragma unroll
    for (int i = 0; i < 8; ++i) { mx[i] = -INFINITY; mn[i] = INFINITY; }

    // ring depth 2
    float4 aB[2];
    float4 wB[2][8];
#pragma unroll
    for (int b = 0; b < 2; ++b) {
        aB[b] = at4[(size_t)b * M + m];
#pragma unroll
        for (int n = 0; n < 8; ++n)
            wB[b][n] = wt4v[(size_t)b * N + n];
    }

#pragma unroll 2
    for (int j = 0; j < 254; ++j) {   // K/4 == 256 quads; tail 254,255
        const int b = j & 1;
        const float4 a = aB[b];
        const f32x2 alo = {a.x, a.y};
        const f32x2 ahi = {a.z, a.w};
#pragma unroll
        for (int n = 0; n < 8; ++n) {
            const float4 w = wB[b][n];
            upd(mx[n], mn[n], pkmul(alo, (f32x2){w.x, w.y}));
            upd(mx[n], mn[n], pkmul(ahi, (f32x2){w.z, w.w}));
        }
        // prefetch j+2 into the freed buffer
        aB[b] = at4[(size_t)(j + 2) * M + m];
#pragma unroll
        for (int n = 0; n < 8; ++n)
            wB[b][n] = wt4v[(size_t)(j + 2) * N + n];
    }
#pragma unroll
    for (int j = 254; j < 256; ++j) {
        const int b = j & 1;
        const float4 a = aB[b];
        const f32x2 alo = {a.x, a.y};
        const f32x2 ahi = {a.z, a.w};
#pragma unroll
        for (int n = 0; n < 8; ++n) {
            const float4 w = wB[b][n];
            upd(mx[n], mn[n], pkmul(alo, (f32x2){w.x, w.y}));
            upd(mx[n], mn[n], pkmul(ahi, (f32x2){w.z, w.w}));
        }
    }

    float4 o0, o1;
    o0.x = mx[0] + mn[0] + bias[n0 + 0];
    o0.y = mx[1] + mn[1] + bias[n0 + 1];
    o0.z = mx[2] + mn[2] + bias[n0 + 2];
    o0.w = mx[3] + mn[3] + bias[n0 + 3];
    o1.x = mx[4] + mn[4] + bias[n0 + 4];
    o1.y = mx[5] + mn[5] + bias[n0 + 5];
    o1.z = mx[6] + mn[6] + bias[n0 + 6];
    o1.w = mx[7] + mn[7] + bias[n0 + 7];
    float4* Crow = (float4*)(C + (size_t)m * N + n0);
    Crow[0] = o0;
    Crow[1] = o1;
}

// ---- fallback (proven R2 kernel, 129 us) ----
#define BM 64
#define BN 64
#define BK 32
#define LDSW 68

__device__ __forceinline__ void mam_update_fb(float& mx, float& mn, float p0, float p1) {
    float nmx, nmn;
    asm("v_max3_f32 %0, %1, %2, %3" : "=v"(nmx) : "v"(p0), "v"(p1), "v"(mx));
    asm("v_min3_f32 %0, %1, %2, %3" : "=v"(nmn) : "v"(p0), "v"(p1), "v"(mn));
    mx = nmx;
    mn = nmn;
}

__global__ __launch_bounds__(256) void mam_fallback(
    const float* __restrict__ A, const float* __restrict__ W,
    const float* __restrict__ bias, float* __restrict__ C,
    int M, int N, int K)
{
    __shared__ float As[BK][LDSW];
    __shared__ float Ws[BK][LDSW];

    const int t  = threadIdx.x;
    const int tx = t & 15;
    const int ty = t >> 4;
    const int m0 = blockIdx.y * BM;
    const int n0 = blockIdx.x * BN;
    const int r  = t >> 3;
    const int kq = t & 7;

    const float* Aptr = A + (size_t)(m0 + r) * K + kq * 4;
    const float* Wptr = W + (size_t)(n0 + r) * K + kq * 4;

    float vmax[4][4], vmin[4][4];
#pragma unroll
    for (int i = 0; i < 4; ++i)
#pragma unroll
        for (int j = 0; j < 4; ++j) {
            vmax[i][j] = -INFINITY;
            vmin[i][j] =  INFINITY;
        }

    for (int k0 = 0; k0 < K; k0 += BK) {
        float4 a0 = *(const float4*)(Aptr);
        float4 a1 = *(const float4*)(Aptr + (size_t)32 * K);
        float4 w0 = *(const float4*)(Wptr);
        float4 w1 = *(const float4*)(Wptr + (size_t)32 * K);
        Aptr += BK;
        Wptr += BK;

        const int kk = kq * 4;
        As[kk + 0][r]      = a0.x;
        As[kk + 1][r]      = a0.y;
        As[kk + 2][r]      = a0.z;
        As[kk + 3][r]      = a0.w;
        As[kk + 0][r + 32] = a1.x;
        As[kk + 1][r + 32] = a1.y;
        As[kk + 2][r + 32] = a1.z;
        As[kk + 3][r + 32] = a1.w;

        Ws[kk + 0][r]      = w0.x;
        Ws[kk + 1][r]      = w0.y;
        Ws[kk + 2][r]      = w0.z;
        Ws[kk + 3][r]      = w0.w;
        Ws[kk + 0][r + 32] = w1.x;
        Ws[kk + 1][r + 32] = w1.y;
        Ws[kk + 2][r + 32] = w1.z;
        Ws[kk + 3][r + 32] = w1.w;

        __syncthreads();

#pragma unroll
        for (int k = 0; k < BK; k += 2) {
            float4 ta0 = *(const float4*)&As[k    ][ty * 4];
            float4 ta1 = *(const float4*)&As[k + 1][ty * 4];
            float4 tb0 = *(const float4*)&Ws[k    ][tx * 4];
            float4 tb1 = *(const float4*)&Ws[k + 1][tx * 4];

            float a0v[4] = {ta0.x, ta0.y, ta0.z, ta0.w};
            float a1v[4] = {ta1.x, ta1.y, ta1.z, ta1.w};
            float b0v[4] = {tb0.x, tb0.y, tb0.z, tb0.w};
            float b1v[4] = {tb1.x, tb1.y, tb1.z, tb1.w};

#pragma unroll
            for (int i = 0; i < 4; ++i)
#pragma unroll
                for (int j = 0; j < 4; ++j) {
                    float p0 = a0v[i] * b0v[j];
                    float p1 = a1v[i] * b1v[j];
                    mam_update_fb(vmax[i][j], vmin[i][j], p0, p1);
                }
        }
        __syncthreads();
    }

    float4 bv = *(const float4*)(bias + n0 + tx * 4);
#pragma unroll
    for (int i = 0; i < 4; ++i) {
        float4 o;
        o.x = vmax[i][0] + vmin[i][0] + bv.x;
        o.y = vmax[i][1] + vmin[i][1] + bv.y;
        o.z = vmax[i][2] + vmin[i][2] + bv.z;
        o.w = vmax[i][3] + vmin[i][3] + bv.w;
        *(float4*)(C + (size_t)(m0 + ty * 4 + i) * N + n0 + tx * 4) = o;
    }
}

extern "C" void kernel_launch(void* const* d_in, const int* in_sizes, int n_in,
                              void* d_out, int out_size, void* d_ws, size_t ws_size,
                              hipStream_t stream) {
    const float* x    = (const float*)d_in[0];
    const float* w    = (const float*)d_in[1];
    const float* bias = (const float*)d_in[2];
    float* out = (float*)d_out;

    const int N = in_sizes[2];
    const int K = in_sizes[1] / N;
    const int M = in_sizes[0] / K;

    const size_t needA = (size_t)M * K * sizeof(float);   // 8 MB
    const size_t needW = (size_t)N * K * sizeof(float);   // 4 MB
    const bool fast_ok = (ws_size >= needA + needW) && (K == 1024) &&
                         (M % 256 == 0) && (N % 64 == 0) && (M % 64 == 0);

    if (fast_ok) {
        float4* at4 = (float4*)d_ws;
        float4* wt4 = (float4*)((char*)d_ws + needA);
        dim3 tga(K / 64, M / 64);
        transpose_k4<<<tga, 256, 0, stream>>>(x, at4, M, K);
        dim3 tgw(K / 64, N / 64);
        transpose_k4<<<tgw, 256, 0, stream>>>(w, wt4, N, K);
        dim3 mg(N / 8, M / 256);   // (128, 8) = 1024 blocks
        mam_main<<<mg, 256, 0, stream>>>(at4, wt4, bias, out, M, N, K);
    } else {
        dim3 grid(N / BN, M / BM);
        mam_fallback<<<grid, 256, 0, stream>>>(x, w, bias, out, M, N, K);
    }
}

// Round 9
// 190.003 us; speedup vs baseline: 1.7201x; 1.7201x over previous
//
#include <hip/hip_runtime.h>
#include <math.h>

// MAM dense: C[m,n] = max_k(A[m,k]*W[n,k]) + min_k(A[m,k]*W[n,k]) + bias[n]
// A: [M,K] fp32, W: [N,K] fp32 (torch layout), C: [M,N]
//
// R9: dual-pipe operand split. Pipe inventory (measured R2/R8): LDS ~85-128
// B/cyc/CU, VMEM return ~64 B/cyc/CU (per-lane bytes; broadcast amplifies
// 64x -- R8's lesson). R2 put A+W both on LDS (2 B/prod -> 42 prod/cyc cap).
// Now: A via LDS (1 B/prod), W via per-lane VMEM from k-major Wt4[j][n]
// (1 B/prod). 64x64 tile, 4x4 micro, 256 thr, 512 blocks = 8 waves/CU.
// Per j(4k)/CU: VMEM 512 cyc = VALU 512 = period -> 131k cyc = 55 us ideal.
// W prefetch distance 2; A staging barriers halved vs R2.

#define BK 32
#define LDSA 68  // LDS row stride (floats)

__device__ __forceinline__ void mam_upd(float& mx, float& mn, float p0, float p1) {
    float nmx, nmn;
    asm("v_max3_f32 %0, %1, %2, %3" : "=v"(nmx) : "v"(p0), "v"(p1), "v"(mx));
    asm("v_min3_f32 %0, %1, %2, %3" : "=v"(nmn) : "v"(p0), "v"(p1), "v"(mn));
    mx = nmx;
    mn = nmn;
}

// ---- pre-pass: Wt4[j][n] = float4(W[n][4j..4j+3]), row-major X[R][K] ----
__global__ __launch_bounds__(256) void transpose_k4(
    const float* __restrict__ X, float4* __restrict__ out, int R, int K)
{
    __shared__ float4 T[16][65];
    const int t = threadIdx.x;
    const int r = t >> 3;        // 0..31
    const int c = t & 7;         // 0..7
    const int r0 = blockIdx.y * 64;
    const int k0 = blockIdx.x * 64;

    const float4* Xr0 = (const float4*)(X + (size_t)(r0 + r) * K + k0);
    const float4* Xr1 = (const float4*)(X + (size_t)(r0 + r + 32) * K + k0);
    T[c][r]          = Xr0[c];
    T[c + 8][r]      = Xr0[c + 8];
    T[c][r + 32]     = Xr1[c];
    T[c + 8][r + 32] = Xr1[c + 8];
    __syncthreads();

    const int rl = t & 63;
    const int jq = t >> 6;       // 0..3
    const int j0 = blockIdx.x * 16;
#pragma unroll
    for (int q = 0; q < 4; ++q) {
        const int jl = jq * 4 + q;
        out[(size_t)(j0 + jl) * R + r0 + rl] = T[jl][rl];
    }
}

// ---- main: A via LDS, W via per-lane VMEM stream ----
__global__ __launch_bounds__(256) void mam_hybrid(
    const float* __restrict__ A, const float4* __restrict__ wt4,
    const float* __restrict__ bias, float* __restrict__ C,
    int M, int N, int K)
{
    __shared__ float As[BK][LDSA];

    const int t  = threadIdx.x;
    const int tx = t & 15;   // n micro (4 cols)
    const int ty = t >> 4;   // m micro (4 rows)
    const int m0 = blockIdx.y * 64;
    const int n0 = blockIdx.x * 64;

    const int r  = t >> 3;   // A staging row 0..31
    const int kq = t & 7;    // A staging k-quad

    const float* Aptr = A + (size_t)(m0 + r) * K + kq * 4;

    // per-lane W stream: 4 consecutive float4 (n = n0+tx*4 .. +3) per j
    const float4* wp = wt4 + n0 + tx * 4;
    const int J = K >> 2;    // 256

    float vmax[4][4], vmin[4][4];
#pragma unroll
    for (int i = 0; i < 4; ++i)
#pragma unroll
        for (int j = 0; j < 4; ++j) {
            vmax[i][j] = -INFINITY;
            vmin[i][j] =  INFINITY;
        }

    // W ring: buffers for j and j+1; prefetch distance 2
    float4 wb[2][4];
#pragma unroll
    for (int c = 0; c < 4; ++c) {
        wb[0][c] = wp[c];
        wb[1][c] = wp[(size_t)N + c];
    }

    int jg = 0;
    for (int s = 0; s < K / BK; ++s) {
        // ---- stage A tile (64 m x 32 k) into LDS, transposed ----
        float4 a0 = *(const float4*)(Aptr);
        float4 a1 = *(const float4*)(Aptr + (size_t)32 * K);
        Aptr += BK;

        const int kk = kq * 4;
        As[kk + 0][r]      = a0.x;
        As[kk + 1][r]      = a0.y;
        As[kk + 2][r]      = a0.z;
        As[kk + 3][r]      = a0.w;
        As[kk + 0][r + 32] = a1.x;
        As[kk + 1][r + 32] = a1.y;
        As[kk + 2][r + 32] = a1.z;
        As[kk + 3][r + 32] = a1.w;

        __syncthreads();

#pragma unroll
        for (int jl = 0; jl < BK / 4; ++jl) {
            const int b = jg & 1;
            const float4 w0 = wb[b][0];
            const float4 w1 = wb[b][1];
            const float4 w2 = wb[b][2];
            const float4 w3 = wb[b][3];

            // prefetch j+2 into the freed buffer (uniform branch)
            if (jg < 254) {
                const size_t off = (size_t)(jg + 2) * N;
#pragma unroll
                for (int c = 0; c < 4; ++c)
                    wb[b][c] = wp[off + c];
            }

            // A fragments: 4 k-rows x 4 m each (b128 reads, quad-broadcast)
            const int kb = jl * 4;
            float4 ta0 = *(const float4*)&As[kb + 0][ty * 4];
            float4 ta1 = *(const float4*)&As[kb + 1][ty * 4];
            float4 ta2 = *(const float4*)&As[kb + 2][ty * 4];
            float4 ta3 = *(const float4*)&As[kb + 3][ty * 4];

            float a0v[4] = {ta0.x, ta0.y, ta0.z, ta0.w};
            float a1v[4] = {ta1.x, ta1.y, ta1.z, ta1.w};
            float a2v[4] = {ta2.x, ta2.y, ta2.z, ta2.w};
            float a3v[4] = {ta3.x, ta3.y, ta3.z, ta3.w};

            const float4 wv[4] = {w0, w1, w2, w3};
#pragma unroll
            for (int c = 0; c < 4; ++c) {
                const float4 w = wv[c];
#pragma unroll
                for (int i = 0; i < 4; ++i) {
                    float p0 = a0v[i] * w.x;
                    float p1 = a1v[i] * w.y;
                    mam_upd(vmax[i][c], vmin[i][c], p0, p1);
                    float p2 = a2v[i] * w.z;
                    float p3 = a3v[i] * w.w;
                    mam_upd(vmax[i][c], vmin[i][c], p2, p3);
                }
            }
            ++jg;
        }

        __syncthreads();
    }

    float4 bv = *(const float4*)(bias + n0 + tx * 4);
    float bvv[4] = {bv.x, bv.y, bv.z, bv.w};
#pragma unroll
    for (int i = 0; i < 4; ++i) {
        float4 o;
        o.x = vmax[i][0] + vmin[i][0] + bvv[0];
        o.y = vmax[i][1] + vmin[i][1] + bvv[1];
        o.z = vmax[i][2] + vmin[i][2] + bvv[2];
        o.w = vmax[i][3] + vmin[i][3] + bvv[3];
        *(float4*)(C + (size_t)(m0 + ty * 4 + i) * N + n0 + tx * 4) = o;
    }
}

// ---- fallback (proven R2 kernel, 129 us) ----
#define BM 64
#define BN 64
#define LDSW 68

__global__ __launch_bounds__(256) void mam_fallback(
    const float* __restrict__ A, const float* __restrict__ W,
    const float* __restrict__ bias, float* __restrict__ C,
    int M, int N, int K)
{
    __shared__ float Asf[BK][LDSW];
    __shared__ float Wsf[BK][LDSW];

    const int t  = threadIdx.x;
    const int tx = t & 15;
    const int ty = t >> 4;
    const int m0 = blockIdx.y * BM;
    const int n0 = blockIdx.x * BN;
    const int r  = t >> 3;
    const int kq = t & 7;

    const float* Aptr = A + (size_t)(m0 + r) * K + kq * 4;
    const float* Wptr = W + (size_t)(n0 + r) * K + kq * 4;

    float vmax[4][4], vmin[4][4];
#pragma unroll
    for (int i = 0; i < 4; ++i)
#pragma unroll
        for (int j = 0; j < 4; ++j) {
            vmax[i][j] = -INFINITY;
            vmin[i][j] =  INFINITY;
        }

    for (int k0 = 0; k0 < K; k0 += BK) {
        float4 a0 = *(const float4*)(Aptr);
        float4 a1 = *(const float4*)(Aptr + (size_t)32 * K);
        float4 w0 = *(const float4*)(Wptr);
        float4 w1 = *(const float4*)(Wptr + (size_t)32 * K);
        Aptr += BK;
        Wptr += BK;

        const int kk = kq * 4;
        Asf[kk + 0][r]      = a0.x;
        Asf[kk + 1][r]      = a0.y;
        Asf[kk + 2][r]      = a0.z;
        Asf[kk + 3][r]      = a0.w;
        Asf[kk + 0][r + 32] = a1.x;
        Asf[kk + 1][r + 32] = a1.y;
        Asf[kk + 2][r + 32] = a1.z;
        Asf[kk + 3][r + 32] = a1.w;

        Wsf[kk + 0][r]      = w0.x;
        Wsf[kk + 1][r]      = w0.y;
        Wsf[kk + 2][r]      = w0.z;
        Wsf[kk + 3][r]      = w0.w;
        Wsf[kk + 0][r + 32] = w1.x;
        Wsf[kk + 1][r + 32] = w1.y;
        Wsf[kk + 2][r + 32] = w1.z;
        Wsf[kk + 3][r + 32] = w1.w;

        __syncthreads();

#pragma unroll
        for (int k = 0; k < BK; k += 2) {
            float4 ta0 = *(const float4*)&Asf[k    ][ty * 4];
            float4 ta1 = *(const float4*)&Asf[k + 1][ty * 4];
            float4 tb0 = *(const float4*)&Wsf[k    ][tx * 4];
            float4 tb1 = *(const float4*)&Wsf[k + 1][tx * 4];

            float a0v[4] = {ta0.x, ta0.y, ta0.z, ta0.w};
            float a1v[4] = {ta1.x, ta1.y, ta1.z, ta1.w};
            float b0v[4] = {tb0.x, tb0.y, tb0.z, tb0.w};
            float b1v[4] = {tb1.x, tb1.y, tb1.z, tb1.w};

#pragma unroll
            for (int i = 0; i < 4; ++i)
#pragma unroll
                for (int j = 0; j < 4; ++j) {
                    float p0 = a0v[i] * b0v[j];
                    float p1 = a1v[i] * b1v[j];
                    mam_upd(vmax[i][j], vmin[i][j], p0, p1);
                }
        }
        __syncthreads();
    }

    float4 bv = *(const float4*)(bias + n0 + tx * 4);
#pragma unroll
    for (int i = 0; i < 4; ++i) {
        float4 o;
        o.x = vmax[i][0] + vmin[i][0] + bv.x;
        o.y = vmax[i][1] + vmin[i][1] + bv.y;
        o.z = vmax[i][2] + vmin[i][2] + bv.z;
        o.w = vmax[i][3] + vmin[i][3] + bv.w;
        *(float4*)(C + (size_t)(m0 + ty * 4 + i) * N + n0 + tx * 4) = o;
    }
}

extern "C" void kernel_launch(void* const* d_in, const int* in_sizes, int n_in,
                              void* d_out, int out_size, void* d_ws, size_t ws_size,
                              hipStream_t stream) {
    const float* x    = (const float*)d_in[0];
    const float* w    = (const float*)d_in[1];
    const float* bias = (const float*)d_in[2];
    float* out = (float*)d_out;

    const int N = in_sizes[2];
    const int K = in_sizes[1] / N;
    const int M = in_sizes[0] / K;

    const size_t needW = (size_t)N * K * sizeof(float);   // 4 MB
    const bool fast_ok = (ws_size >= needW) && (K == 1024) &&
                         (M % 64 == 0) && (N % 64 == 0);

    if (fast_ok) {
        float4* wt4 = (float4*)d_ws;
        dim3 tgw(K / 64, N / 64);
        transpose_k4<<<tgw, 256, 0, stream>>>(w, wt4, N, K);
        dim3 mg(N / 64, M / 64);   // (16, 32) = 512 blocks
        mam_hybrid<<<mg, 256, 0, stream>>>(x, wt4, bias, out, M, N, K);
    } else {
        dim3 grid(N / BN, M / BM);
        mam_fallback<<<grid, 256, 0, stream>>>(x, w, bias, out, M, N, K);
    }
}

// Round 10
// 154.807 us; speedup vs baseline: 2.1112x; 1.2274x over previous
//
#include <hip/hip_runtime.h>
#include <math.h>

// MAM dense: C[m,n] = max_k(A[m,k]*W[n,k]) + min_k(A[m,k]*W[n,k]) + bias[n]
// A: [M,K] fp32, W: [N,K] fp32 (torch layout), C: [M,N]
//
// R10: register-reuse attack. Duration math R2/R5/R9: throughput was always
// (pipe B/cyc) / (operand B/product); 4x4 micro = 2 B/prod -> 42 prod/cyc cap.
// 8x8 micro = 1 B/prod -> LDS demand (123k cyc/CU) < VALU demand (131k/SIMD)
// -> VALU-bound, 54.6 us floor. Occupancy kept via IN-BLOCK split-K: 64x64
// tile, 4 waves/block, wave w owns k-range [w*256, w*256+256) with its own
// LDS staging strip -> NO barriers in the main loop (same-wave DS ordering).
// Cross-wave merge: 4 sequential LDS rounds at the end. 512 blocks = 8 w/CU.

#define TS 64
#define BK 16
#define LDSP 68

__device__ __forceinline__ void mam_upd(float& mx, float& mn, float p0, float p1) {
    float nmx, nmn;
    asm("v_max3_f32 %0, %1, %2, %3" : "=v"(nmx) : "v"(p0), "v"(p1), "v"(mx));
    asm("v_min3_f32 %0, %1, %2, %3" : "=v"(nmn) : "v"(p0), "v"(p1), "v"(mn));
    mx = nmx;
    mn = nmn;
}

__global__ __launch_bounds__(256, 2) void mam_sk(
    const float* __restrict__ A, const float* __restrict__ W,
    const float* __restrict__ bias, float* __restrict__ C,
    int M, int N, int K)
{
    __shared__ float sA[4][BK][LDSP];   // per-wave staging strips (17 KB)
    __shared__ float sW[4][BK][LDSP];   // 17 KB
    __shared__ float cmx[TS * TS];      // combine buffers (16 KB)
    __shared__ float cmn[TS * TS];      // 16 KB

    const int t    = threadIdx.x;
    const int w    = t >> 6;        // k-group == wave id
    const int lane = t & 63;
    const int ty   = lane >> 3;     // m micro thread (8 rows)
    const int tx   = lane & 7;      // n micro thread (8 cols)
    const int m0   = blockIdx.y * TS;
    const int n0   = blockIdx.x * TS;
    const int kc   = K >> 2;        // k per group (256)
    const int kb0  = w * kc;

    const int sr = lane >> 2;       // staging row 0..15 (stride 16)
    const int sc = lane & 3;        // staging k-quad 0..3

    const float* Ap = A + (size_t)(m0 + sr) * K + kb0 + sc * 4;
    const float* Wp = W + (size_t)(n0 + sr) * K + kb0 + sc * 4;

    float mx[8][8], mn[8][8];
#pragma unroll
    for (int i = 0; i < 8; ++i)
#pragma unroll
        for (int j = 0; j < 8; ++j) {
            mx[i][j] = -INFINITY;
            mn[i][j] =  INFINITY;
        }

    float4 ra[4], rw[4];
#pragma unroll
    for (int q = 0; q < 4; ++q) {
        ra[q] = *(const float4*)(Ap + (size_t)q * 16 * K);
        rw[q] = *(const float4*)(Wp + (size_t)q * 16 * K);
    }
    Ap += BK;
    Wp += BK;

    const int nStages = kc / BK;    // 16
    for (int s = 0; s < nStages; ++s) {
        // scatter current stage into this wave's strip, k-major (no barrier:
        // same-wave DS ops are ordered; other waves never touch this strip)
#pragma unroll
        for (int q = 0; q < 4; ++q) {
            const int mI = sr + q * 16;
            sA[w][sc * 4 + 0][mI] = ra[q].x;
            sA[w][sc * 4 + 1][mI] = ra[q].y;
            sA[w][sc * 4 + 2][mI] = ra[q].z;
            sA[w][sc * 4 + 3][mI] = ra[q].w;
            sW[w][sc * 4 + 0][mI] = rw[q].x;
            sW[w][sc * 4 + 1][mI] = rw[q].y;
            sW[w][sc * 4 + 2][mI] = rw[q].z;
            sW[w][sc * 4 + 3][mI] = rw[q].w;
        }
        // prefetch next stage while computing this one
        if (s + 1 < nStages) {
#pragma unroll
            for (int q = 0; q < 4; ++q) {
                ra[q] = *(const float4*)(Ap + (size_t)q * 16 * K);
                rw[q] = *(const float4*)(Wp + (size_t)q * 16 * K);
            }
            Ap += BK;
            Wp += BK;
        }

#pragma unroll
        for (int k = 0; k < BK; k += 2) {
            float4 a00 = *(const float4*)&sA[w][k    ][ty * 8];
            float4 a01 = *(const float4*)&sA[w][k    ][ty * 8 + 4];
            float4 a10 = *(const float4*)&sA[w][k + 1][ty * 8];
            float4 a11 = *(const float4*)&sA[w][k + 1][ty * 8 + 4];
            float4 w00 = *(const float4*)&sW[w][k    ][tx * 8];
            float4 w01 = *(const float4*)&sW[w][k    ][tx * 8 + 4];
            float4 w10 = *(const float4*)&sW[w][k + 1][tx * 8];
            float4 w11 = *(const float4*)&sW[w][k + 1][tx * 8 + 4];

            float a0[8] = {a00.x, a00.y, a00.z, a00.w, a01.x, a01.y, a01.z, a01.w};
            float a1[8] = {a10.x, a10.y, a10.z, a10.w, a11.x, a11.y, a11.z, a11.w};
            float b0[8] = {w00.x, w00.y, w00.z, w00.w, w01.x, w01.y, w01.z, w01.w};
            float b1[8] = {w10.x, w10.y, w10.z, w10.w, w11.x, w11.y, w11.z, w11.w};

#pragma unroll
            for (int i = 0; i < 8; ++i)
#pragma unroll
                for (int j = 0; j < 8; ++j) {
                    float p0 = a0[i] * b0[j];
                    float p1 = a1[i] * b1[j];
                    mam_upd(mx[i][j], mn[i][j], p0, p1);
                }
        }
    }

    // ---- cross-wave combine: sequential merge rounds through LDS ----
    for (int rnd = 0; rnd < 4; ++rnd) {
        if (w == rnd) {
#pragma unroll
            for (int i = 0; i < 8; ++i)
#pragma unroll
                for (int j = 0; j < 8; ++j) {
                    const int idx = (ty * 8 + i) * TS + tx * 8 + j;
                    if (rnd == 0) {
                        cmx[idx] = mx[i][j];
                        cmn[idx] = mn[i][j];
                    } else {
                        cmx[idx] = fmaxf(cmx[idx], mx[i][j]);
                        cmn[idx] = fminf(cmn[idx], mn[i][j]);
                    }
                }
        }
        __syncthreads();
    }

    // ---- bias + store: wave w writes micro-rows i = {2w, 2w+1} ----
    float4 blo = *(const float4*)(bias + n0 + tx * 8);
    float4 bhi = *(const float4*)(bias + n0 + tx * 8 + 4);
#pragma unroll
    for (int i2 = 0; i2 < 2; ++i2) {
        const int i   = w * 2 + i2;
        const int row = ty * 8 + i;
        const int idx = row * TS + tx * 8;
        float4 o0, o1;
        o0.x = cmx[idx + 0] + cmn[idx + 0] + blo.x;
        o0.y = cmx[idx + 1] + cmn[idx + 1] + blo.y;
        o0.z = cmx[idx + 2] + cmn[idx + 2] + blo.z;
        o0.w = cmx[idx + 3] + cmn[idx + 3] + blo.w;
        o1.x = cmx[idx + 4] + cmn[idx + 4] + bhi.x;
        o1.y = cmx[idx + 5] + cmn[idx + 5] + bhi.y;
        o1.z = cmx[idx + 6] + cmn[idx + 6] + bhi.z;
        o1.w = cmx[idx + 7] + cmn[idx + 7] + bhi.w;
        float4* p = (float4*)(C + (size_t)(m0 + row) * N + n0 + tx * 8);
        p[0] = o0;
        p[1] = o1;
    }
}

// ---- fallback (proven R2 kernel) for shapes the fast path can't take ----
#define BM 64
#define BN 64
#define FBK 32
#define LDSW 68

__global__ __launch_bounds__(256) void mam_fallback(
    const float* __restrict__ A, const float* __restrict__ W,
    const float* __restrict__ bias, float* __restrict__ C,
    int M, int N, int K)
{
    __shared__ float Asf[FBK][LDSW];
    __shared__ float Wsf[FBK][LDSW];

    const int t  = threadIdx.x;
    const int tx = t & 15;
    const int ty = t >> 4;
    const int m0 = blockIdx.y * BM;
    const int n0 = blockIdx.x * BN;
    const int r  = t >> 3;
    const int kq = t & 7;

    const float* Aptr = A + (size_t)(m0 + r) * K + kq * 4;
    const float* Wptr = W + (size_t)(n0 + r) * K + kq * 4;

    float vmax[4][4], vmin[4][4];
#pragma unroll
    for (int i = 0; i < 4; ++i)
#pragma unroll
        for (int j = 0; j < 4; ++j) {
            vmax[i][j] = -INFINITY;
            vmin[i][j] =  INFINITY;
        }

    for (int k0 = 0; k0 < K; k0 += FBK) {
        float4 a0 = *(const float4*)(Aptr);
        float4 a1 = *(const float4*)(Aptr + (size_t)32 * K);
        float4 w0 = *(const float4*)(Wptr);
        float4 w1 = *(const float4*)(Wptr + (size_t)32 * K);
        Aptr += FBK;
        Wptr += FBK;

        const int kk = kq * 4;
        Asf[kk + 0][r]      = a0.x;
        Asf[kk + 1][r]      = a0.y;
        Asf[kk + 2][r]      = a0.z;
        Asf[kk + 3][r]      = a0.w;
        Asf[kk + 0][r + 32] = a1.x;
        Asf[kk + 1][r + 32] = a1.y;
        Asf[kk + 2][r + 32] = a1.z;
        Asf[kk + 3][r + 32] = a1.w;

        Wsf[kk + 0][r]      = w0.x;
        Wsf[kk + 1][r]      = w0.y;
        Wsf[kk + 2][r]      = w0.z;
        Wsf[kk + 3][r]      = w0.w;
        Wsf[kk + 0][r + 32] = w1.x;
        Wsf[kk + 1][r + 32] = w1.y;
        Wsf[kk + 2][r + 32] = w1.z;
        Wsf[kk + 3][r + 32] = w1.w;

        __syncthreads();

#pragma unroll
        for (int k = 0; k < FBK; k += 2) {
            float4 ta0 = *(const float4*)&Asf[k    ][ty * 4];
            float4 ta1 = *(const float4*)&Asf[k + 1][ty * 4];
            float4 tb0 = *(const float4*)&Wsf[k    ][tx * 4];
            float4 tb1 = *(const float4*)&Wsf[k + 1][tx * 4];

            float a0v[4] = {ta0.x, ta0.y, ta0.z, ta0.w};
            float a1v[4] = {ta1.x, ta1.y, ta1.z, ta1.w};
            float b0v[4] = {tb0.x, tb0.y, tb0.z, tb0.w};
            float b1v[4] = {tb1.x, tb1.y, tb1.z, tb1.w};

#pragma unroll
            for (int i = 0; i < 4; ++i)
#pragma unroll
                for (int j = 0; j < 4; ++j) {
                    float p0 = a0v[i] * b0v[j];
                    float p1 = a1v[i] * b1v[j];
                    mam_upd(vmax[i][j], vmin[i][j], p0, p1);
                }
        }
        __syncthreads();
    }

    float4 bv = *(const float4*)(bias + n0 + tx * 4);
#pragma unroll
    for (int i = 0; i < 4; ++i) {
        float4 o;
        o.x = vmax[i][0] + vmin[i][0] + bv.x;
        o.y = vmax[i][1] + vmin[i][1] + bv.y;
        o.z = vmax[i][2] + vmin[i][2] + bv.z;
        o.w = vmax[i][3] + vmin[i][3] + bv.w;
        *(float4*)(C + (size_t)(m0 + ty * 4 + i) * N + n0 + tx * 4) = o;
    }
}

extern "C" void kernel_launch(void* const* d_in, const int* in_sizes, int n_in,
                              void* d_out, int out_size, void* d_ws, size_t ws_size,
                              hipStream_t stream) {
    const float* x    = (const float*)d_in[0];
    const float* w    = (const float*)d_in[1];
    const float* bias = (const float*)d_in[2];
    float* out = (float*)d_out;

    const int N = in_sizes[2];
    const int K = in_sizes[1] / N;
    const int M = in_sizes[0] / K;

    // fast path needs K divisible by 4*BK and 64-multiple tiles; no workspace.
    const bool fast_ok = (K % (4 * BK) == 0) && (M % TS == 0) && (N % TS == 0);

    if (fast_ok) {
        dim3 grid(N / TS, M / TS);   // (16, 32) = 512 blocks
        mam_sk<<<grid, 256, 0, stream>>>(x, w, bias, out, M, N, K);
    } else {
        dim3 grid(N / BN, M / BM);
        mam_fallback<<<grid, 256, 0, stream>>>(x, w, bias, out, M, N, K);
    }
}